// Round 10
// baseline (144.348 us; speedup 1.0000x reference)
//
#include <hip/hip_runtime.h>

// Fused cross-attention: out = concat(dec, softmax_e(enc·dec^T)^T-weighted enc)
// B=8, T_enc=T_dec=2048, D=512, fp32 in/out.
// R10: R9 with phase-B reordered for the vmcnt-drain model: global loads for
//     ch+2 issued at TOP of phase B (covered by softmax+PV before B2's
//     compiler-emitted vmcnt(0) drain), cvt hoisted to free st regs first,
//     Khi-writes moved after PV. Math/layout/barriers identical to R9.

typedef _Float16 f16;
typedef f16 f16x8 __attribute__((ext_vector_type(8)));
typedef f16 f16x4 __attribute__((ext_vector_type(4)));
typedef float f32x4 __attribute__((ext_vector_type(4)));

#define NB 8
#define TE 2048
#define TD 2048
#define DD 512
#define TBLK 64
#define EBLK 32
#define NCH (TE / EBLK)

// LDS layout (bytes) — audited: end 121664 < 163840
#define OKHI 0          // [32 e][512 d] f16 = 32768B, 1024B swizzled rows (QK A)
#define OKT  32768      // [512 d][40 e] f16 = 40960B, 80B rows, sig-swizzled (PV A)
#define OS4  73728      // 4 kq x [64 t][36 e] f32 = 36864B (144B rows)
#define OP   110592     // 2 x [64 t][40 e] f16 = 10240B, 80B rows
#define OPSZ 5120
#define OAL  120832     // 2 x 64 f32 alpha
#define OLL  121344     // 64 f32 l
#define OFLG 121600     // 2 x 8 u32 rescale flags
#define SMEM_BYTES 121664

__device__ __forceinline__ int swz1k(int row, int byteInRow) {
    return row * 1024 + (byteInRow ^ ((row & 7) << 4));
}

__global__ __launch_bounds__(512, 2)
void attn_fused(const float* __restrict__ enc, const float* __restrict__ dec,
                float* __restrict__ out) {
    __shared__ __align__(16) char sm[SMEM_BYTES];
    const int tid  = threadIdx.x;
    const int b    = blockIdx.x & 7;          // XCD-pinned batch
    const int t0   = (blockIdx.x >> 3) * TBLK;
    const int lane = tid & 63;
    const int wv   = tid >> 6;
    const int li   = lane & 15;
    const int gi   = lane >> 4;
    const int tq   = wv & 1;                  // t-half: rows 32tq..32tq+31
    const int kq   = wv >> 1;                 // k-slice: d in [128kq, 128kq+128)
    const float L2E = 1.44269504088896f;

    const float* encB = enc + (size_t)b * TE * DD;
    const float* decB = dec + (size_t)b * TD * DD;
    float*       outB = out + (size_t)b * TD * (2 * DD);

    // staging map: c4 = d-quad 0..127, rb = e-octet 0..3 (e rows 8rb..8rb+7)
    const int c4 = tid & 127;
    const int rb = tid >> 7;

    // ---- issue K0 loads ----
    f32x4 st[8];
    #pragma unroll
    for (int i = 0; i < 8; ++i)
        st[i] = *(const f32x4*)(encB + (size_t)(8 * rb + i) * DD + 4 * c4);

    // ---- Q fragments (f16) direct from global ----
    f16x8 qF[4][2];
    #pragma unroll
    for (int kk = 0; kk < 4; ++kk)
        #pragma unroll
        for (int tl = 0; tl < 2; ++tl) {
            const float* qp = decB + (size_t)(t0 + 32 * tq + 16 * tl + li) * DD
                            + 128 * kq + 32 * kk + 8 * gi;
            f32x4 q0 = *(const f32x4*)qp;
            f32x4 q1 = *(const f32x4*)(qp + 4);
            f16x8 h;
            #pragma unroll
            for (int j = 0; j < 4; ++j) { h[j] = (f16)q0[j]; h[4 + j] = (f16)q1[j]; }
            qF[kk][tl] = h;
        }

    // ---- cvt K0 -> hvB + Khi-write(0); KT(0) written in iter 0 phase C ----
    f16x4 hvB[8];
    #pragma unroll
    for (int i = 0; i < 8; ++i) {
        f16x4 h4 = {(f16)st[i][0], (f16)st[i][1], (f16)st[i][2], (f16)st[i][3]};
        hvB[i] = h4;
        *(f16x4*)(sm + OKHI + swz1k(8 * rb + i, 8 * c4)) = h4;
    }
    // issue K1 loads
    #pragma unroll
    for (int i = 0; i < 8; ++i)
        st[i] = *(const f32x4*)(encB + (size_t)(EBLK + 8 * rb + i) * DD + 4 * c4);
    __syncthreads();

    // softmax ownership: wave owns t-cols [8wv, 8wv+8); 8 lanes/col, 4 e/lane
    const int cq   = lane & 7;
    const int erq  = lane >> 3;               // 0..7 -> e rows 4erq..4erq+3
    const int tcol = 8 * wv + cq;
    float mrun = -1.0e30f;
    float lpart = 0.0f;                       // per-lane partial of l (4 e-slots)

    f32x4 ctx[4][4];                          // d [64wv,64wv+64) x t [0,64)
    #pragma unroll
    for (int md = 0; md < 4; ++md)
        #pragma unroll
        for (int tt = 0; tt < 4; ++tt)
            ctx[md][tt] = (f32x4){0.f, 0.f, 0.f, 0.f};

    for (int ch = 0; ch < NCH; ++ch) {
        const int pb = ch & 1;
        const int qb = pb ^ 1;
        const bool doPV = (ch > 0);
        const bool more = (ch + 1 < NCH);

        // ---- phase A: QK(ch), S4 partial writes ----
        f32x4 sacc[2][2];
        #pragma unroll
        for (int et = 0; et < 2; ++et)
            #pragma unroll
            for (int tl = 0; tl < 2; ++tl)
                sacc[et][tl] = (f32x4){0.f, 0.f, 0.f, 0.f};
        __builtin_amdgcn_s_setprio(1);
        #pragma unroll
        for (int kk = 0; kk < 4; ++kk) {
            int cb = 256 * kq + 64 * kk + 16 * gi;
            f16x8 aF[2];
            #pragma unroll
            for (int et = 0; et < 2; ++et)
                aF[et] = *(const f16x8*)(sm + OKHI + swz1k(16 * et + li, cb));
            #pragma unroll
            for (int et = 0; et < 2; ++et)
                #pragma unroll
                for (int tl = 0; tl < 2; ++tl)
                    sacc[et][tl] = __builtin_amdgcn_mfma_f32_16x16x32_f16(aF[et], qF[kk][tl], sacc[et][tl], 0, 0, 0);
        }
        __builtin_amdgcn_s_setprio(0);
        #pragma unroll
        for (int et = 0; et < 2; ++et)
            #pragma unroll
            for (int tl = 0; tl < 2; ++tl)
                *(f32x4*)(sm + OS4 + kq * 9216 + (32 * tq + 16 * tl + li) * 144
                          + (16 * et + 4 * gi) * 4) = sacc[et][tl];
        __syncthreads();                                   // B1

        // ---- phase B (drain-aware order):
        //   1. S-reads  2. cvt st->hvA (frees st)  3. issue loads(ch+2)
        //   4. bP/flags  5. softmax  6. PV  7. Khi-write(ch+1)
        f32x4 s4 = (f32x4){0.f, 0.f, 0.f, 0.f};
        #pragma unroll
        for (int bu = 0; bu < 4; ++bu)
            s4 += *(const f32x4*)(sm + OS4 + bu * 9216 + tcol * 144 + 16 * erq);

        f16x4 hvA[8];
        if (more) {
            #pragma unroll
            for (int i = 0; i < 8; ++i) {
                f16x4 h4 = {(f16)st[i][0], (f16)st[i][1], (f16)st[i][2], (f16)st[i][3]};
                hvA[i] = h4;
            }
            if (ch + 2 < NCH) {
                const float* src = encB + (size_t)(ch + 2) * EBLK * DD;
                #pragma unroll
                for (int i = 0; i < 8; ++i)
                    st[i] = *(const f32x4*)(src + (size_t)(8 * rb + i) * DD + 4 * c4);
            }
        }

        bool doR = false;
        f16x8 bP[4];
        if (doPV) {
            const uint4* fp = (const uint4*)(sm + OFLG + 32 * qb);
            uint4 f0 = fp[0], f1 = fp[1];
            doR = (f0.x | f0.y | f0.z | f0.w | f1.x | f1.y | f1.z | f1.w) != 0;
            #pragma unroll
            for (int tt = 0; tt < 4; ++tt)
                bP[tt] = *(const f16x8*)(sm + OP + OPSZ * qb + (16 * tt + li) * 80 + 16 * gi);
        }
        // softmax(ch): fast path has zero cross-lane ops
        {
            float pml = fmaxf(fmaxf(s4[0], s4[1]), fmaxf(s4[2], s4[3]));
            bool trip = pml > mrun + 8.0f;                 // T13 defer-max
            unsigned long long bal = __ballot(trip);
            float alpha = 1.0f;
            if (bal != 0ULL) {                             // wave-uniform slow path
                float pm = pml;
                pm = fmaxf(pm, __shfl_xor(pm, 8));
                pm = fmaxf(pm, __shfl_xor(pm, 16));
                pm = fmaxf(pm, __shfl_xor(pm, 32));
                float mnew = fmaxf(mrun, pm);
                alpha = exp2f((mrun - mnew) * L2E);
                lpart *= alpha;
                mrun = mnew;
            }
            f32x4 p4;
            #pragma unroll
            for (int j = 0; j < 4; ++j) p4[j] = exp2f((s4[j] - mrun) * L2E);
            lpart += p4[0] + p4[1] + p4[2] + p4[3];
            f16x4 pw = {(f16)p4[0], (f16)p4[1], (f16)p4[2], (f16)p4[3]};
            *(f16x4*)(sm + OP + OPSZ * pb + tcol * 80 + 8 * erq) = pw;
            if (erq == 0) *(float*)(sm + OAL + 256 * pb + 4 * tcol) = alpha;
            if (lane == 0) *(unsigned*)(sm + OFLG + 32 * pb + 4 * wv) = (bal != 0ULL) ? 1u : 0u;
        }
        // PV(ch-1): KT holds chunk ch-1 (written in phase C of iter ch-1)
        if (doPV) {
            if (doR) {
                float av[4];
                #pragma unroll
                for (int tt = 0; tt < 4; ++tt)
                    av[tt] = *(const float*)(sm + OAL + 256 * qb + 4 * (16 * tt + li));
                #pragma unroll
                for (int md = 0; md < 4; ++md)
                    #pragma unroll
                    for (int tt = 0; tt < 4; ++tt)
                        #pragma unroll
                        for (int r = 0; r < 4; ++r) ctx[md][tt][r] *= av[tt];
            }
            __builtin_amdgcn_s_setprio(1);
            #pragma unroll
            for (int md = 0; md < 4; ++md) {
                int dv = 64 * wv + 16 * md + li;
                int sig = ((dv >> 3) & 3) << 4;
                f16x8 a = *(const f16x8*)(sm + OKT + dv * 80 + ((16 * gi) ^ sig));
                #pragma unroll
                for (int tt = 0; tt < 4; ++tt)
                    ctx[md][tt] = __builtin_amdgcn_mfma_f32_16x16x32_f16(a, bP[tt], ctx[md][tt], 0, 0, 0);
            }
            __builtin_amdgcn_s_setprio(0);
        }
        // Khi-write(ch+1) from hvA (tail of phase B)
        if (more) {
            #pragma unroll
            for (int i = 0; i < 8; ++i)
                *(f16x4*)(sm + OKHI + swz1k(8 * rb + i, 8 * c4)) = hvA[i];
        }
        __syncthreads();                                   // B2
        // ---- phase C: KT-write(ch) from hvB ----
        #pragma unroll
        for (int k = 0; k < 4; ++k) {
            int d = 4 * c4 + k;
            int sig = ((d >> 3) & 3) << 4;
            f16x8 q8 = {hvB[0][k], hvB[1][k], hvB[2][k], hvB[3][k],
                        hvB[4][k], hvB[5][k], hvB[6][k], hvB[7][k]};
            *(f16x8*)(sm + OKT + d * 80 + ((16 * rb) ^ sig)) = q8;
        }
        if (more) {
            #pragma unroll
            for (int i = 0; i < 8; ++i) hvB[i] = hvA[i];
        }
    }

    __syncthreads();   // KT(NCH-1) written in last phase C

    // ---- final PV(NCH-1) ----
    {
        const int qb2 = (NCH - 1) & 1;
        const uint4* fp = (const uint4*)(sm + OFLG + 32 * qb2);
        uint4 f0 = fp[0], f1 = fp[1];
        bool doR = (f0.x | f0.y | f0.z | f0.w | f1.x | f1.y | f1.z | f1.w) != 0;
        f16x8 bP[4];
        #pragma unroll
        for (int tt = 0; tt < 4; ++tt)
            bP[tt] = *(const f16x8*)(sm + OP + OPSZ * qb2 + (16 * tt + li) * 80 + 16 * gi);
        if (doR) {
            float av[4];
            #pragma unroll
            for (int tt = 0; tt < 4; ++tt)
                av[tt] = *(const float*)(sm + OAL + 256 * qb2 + 4 * (16 * tt + li));
            #pragma unroll
            for (int md = 0; md < 4; ++md)
                #pragma unroll
                for (int tt = 0; tt < 4; ++tt)
                    #pragma unroll
                    for (int r = 0; r < 4; ++r) ctx[md][tt][r] *= av[tt];
        }
        #pragma unroll
        for (int md = 0; md < 4; ++md) {
            int dv = 64 * wv + 16 * md + li;
            int sig = ((dv >> 3) & 3) << 4;
            f16x8 a = *(const f16x8*)(sm + OKT + dv * 80 + ((16 * gi) ^ sig));
            #pragma unroll
            for (int tt = 0; tt < 4; ++tt)
                ctx[md][tt] = __builtin_amdgcn_mfma_f32_16x16x32_f16(a, bP[tt], ctx[md][tt], 0, 0, 0);
        }
    }

    // ---- epilogue: reduce per-lane l partials once, normalize, write ----
    {
        float ps = lpart;
        ps += __shfl_xor(ps, 8);
        ps += __shfl_xor(ps, 16);
        ps += __shfl_xor(ps, 32);
        if (erq == 0) *(float*)(sm + OLL + 4 * tcol) = ps;
    }
    __syncthreads();
    float inv[4];
    #pragma unroll
    for (int tt = 0; tt < 4; ++tt)
        inv[tt] = 1.0f / *(const float*)(sm + OLL + 4 * (16 * tt + li));
    #pragma unroll
    for (int md = 0; md < 4; ++md)
        #pragma unroll
        for (int tt = 0; tt < 4; ++tt) {
            int t = t0 + 16 * tt + li;
            int d = 64 * wv + 16 * md + 4 * gi;
            float4 o;
            o.x = ctx[md][tt][0] * inv[tt];
            o.y = ctx[md][tt][1] * inv[tt];
            o.z = ctx[md][tt][2] * inv[tt];
            o.w = ctx[md][tt][3] * inv[tt];
            *(float4*)(outB + (size_t)t * (2 * DD) + DD + d) = o;
        }
    #pragma unroll
    for (int it = 0; it < TBLK * (DD / 4) / 512; ++it) {
        int i = tid + it * 512;
        int t = i >> 7, cc = i & 127;
        float4 q = ((const float4*)(decB + (size_t)(t0 + t) * DD))[cc];
        ((float4*)(outB + (size_t)(t0 + t) * (2 * DD)))[cc] = q;
    }
}

extern "C" void kernel_launch(void* const* d_in, const int* in_sizes, int n_in,
                              void* d_out, int out_size, void* d_ws, size_t ws_size,
                              hipStream_t stream) {
    const float* enc = (const float*)d_in[0];
    const float* dec = (const float*)d_in[1];
    float* out = (float*)d_out;
    dim3 grid(NB * (TD / TBLK));   // 256 blocks: b = bid&7 (XCD pin), ttile = bid>>3
    dim3 block(512);
    attn_fused<<<grid, block, 0, stream>>>(enc, dec, out);
}

// Round 11
// 143.451 us; speedup vs baseline: 1.0063x; 1.0063x over previous
//
#include <hip/hip_runtime.h>

// Fused cross-attention: out = concat(dec, softmax_e(enc·dec^T)^T-weighted enc)
// B=8, T_enc=T_dec=2048, D=512, fp32 in/out.
// R11: in-register S — wave (et,tl) computes a full 16x16 S subtile with k=512
//      (no S4 partial buffer, no merge round). Cross-et max via 64B MX exchange.
//      Khi rows padded to 1040B (imm-offset aF reads, same bank behavior as XOR).
//      R9 load placement (after PV). Per-lane partial l, T13 defer-max (THR=8).

typedef _Float16 f16;
typedef f16 f16x8 __attribute__((ext_vector_type(8)));
typedef f16 f16x4 __attribute__((ext_vector_type(4)));
typedef float f32x4 __attribute__((ext_vector_type(4)));

#define NB 8
#define TE 2048
#define TD 2048
#define DD 512
#define TBLK 64
#define EBLK 32
#define NCH (TE / EBLK)

// LDS layout (bytes) — audited: end 85824 < 163840
#define OKHI 0          // [32 e][1040B] f16 rows (512 d + 16B pad) = 33280B (QK A)
#define KROW 1040
#define OKT  33280      // [512 d][40 e] f16 = 40960B, 80B rows, sig-swizzled (PV A)
#define OP   74240      // 2 x [64 t][40 e] f16 = 10240B, 80B rows
#define OPSZ 5120
#define OMX  84480      // 8 waves x 16 f32 per-t 16-e max = 512B
#define OAL  84992      // 2 x 64 f32 alpha
#define OLL  85504      // 64 f32 l
#define OFLG 85760      // 2 x 8 u32 rescale flags
#define SMEM_BYTES 85824

__global__ __launch_bounds__(512, 2)
void attn_fused(const float* __restrict__ enc, const float* __restrict__ dec,
                float* __restrict__ out) {
    __shared__ __align__(16) char sm[SMEM_BYTES];
    const int tid  = threadIdx.x;
    const int b    = blockIdx.x & 7;          // XCD-pinned batch
    const int t0   = (blockIdx.x >> 3) * TBLK;
    const int lane = tid & 63;
    const int wv   = tid >> 6;
    const int li   = lane & 15;
    const int gi   = lane >> 4;
    const int et   = wv & 1;                  // e-tile: e in [16et, 16et+16)
    const int tl   = wv >> 1;                 // t-tile: t in [16tl, 16tl+16)
    const float L2E = 1.44269504088896f;

    const float* encB = enc + (size_t)b * TE * DD;
    const float* decB = dec + (size_t)b * TD * DD;
    float*       outB = out + (size_t)b * TD * (2 * DD);

    // staging map: c4 = d-quad 0..127, rb = e-octet 0..3 (e rows 8rb..8rb+7)
    const int c4 = tid & 127;
    const int rb = tid >> 7;

    // ---- issue K0 loads ----
    f32x4 st[8];
    #pragma unroll
    for (int i = 0; i < 8; ++i)
        st[i] = *(const f32x4*)(encB + (size_t)(8 * rb + i) * DD + 4 * c4);

    // ---- Q fragments (f16): full d=512 for t = t0+16tl+li ----
    f16x8 qF[16];
    #pragma unroll
    for (int kk = 0; kk < 16; ++kk) {
        const float* qp = decB + (size_t)(t0 + 16 * tl + li) * DD + 32 * kk + 8 * gi;
        f32x4 q0 = *(const f32x4*)qp;
        f32x4 q1 = *(const f32x4*)(qp + 4);
        f16x8 h;
        #pragma unroll
        for (int j = 0; j < 4; ++j) { h[j] = (f16)q0[j]; h[4 + j] = (f16)q1[j]; }
        qF[kk] = h;
    }

    // ---- cvt K0 -> hvB + Khi-write(0); KT(0) written in iter 0 phase C ----
    char* const kWr = sm + OKHI + (8 * rb) * KROW + 8 * c4;
    f16x4 hvB[8];
    #pragma unroll
    for (int i = 0; i < 8; ++i) {
        f16x4 h4 = {(f16)st[i][0], (f16)st[i][1], (f16)st[i][2], (f16)st[i][3]};
        hvB[i] = h4;
        *(f16x4*)(kWr + i * KROW) = h4;
    }
    // issue K1 loads
    #pragma unroll
    for (int i = 0; i < 8; ++i)
        st[i] = *(const f32x4*)(encB + (size_t)(EBLK + 8 * rb + i) * DD + 4 * c4);
    __syncthreads();

    // per-lane softmax state: lane owns t = 16tl+li, e-slots 16et+4gi+{0..3}
    float mrun = -1.0e30f;
    float lpart = 0.0f;

    const char* const aBase = sm + OKHI + (16 * et + li) * KROW + 16 * gi;

    f32x4 ctx[4][4];                          // d [64wv,64wv+64) x t [0,64)
    #pragma unroll
    for (int md = 0; md < 4; ++md)
        #pragma unroll
        for (int tt = 0; tt < 4; ++tt)
            ctx[md][tt] = (f32x4){0.f, 0.f, 0.f, 0.f};

    for (int ch = 0; ch < NCH; ++ch) {
        const int pb = ch & 1;
        const int qb = pb ^ 1;
        const bool doPV = (ch > 0);
        const bool more = (ch + 1 < NCH);

        // ---- phase A: QK(ch) full-k into one 16x16 subtile; MX write ----
        f32x4 s0 = (f32x4){0.f, 0.f, 0.f, 0.f};
        f32x4 s1 = (f32x4){0.f, 0.f, 0.f, 0.f};
        __builtin_amdgcn_s_setprio(1);
        #pragma unroll
        for (int kk = 0; kk < 8; ++kk) {
            f16x8 aF = *(const f16x8*)(aBase + 64 * kk);
            s0 = __builtin_amdgcn_mfma_f32_16x16x32_f16(aF, qF[kk], s0, 0, 0, 0);
        }
        #pragma unroll
        for (int kk = 8; kk < 16; ++kk) {
            f16x8 aF = *(const f16x8*)(aBase + 64 * kk);
            s1 = __builtin_amdgcn_mfma_f32_16x16x32_f16(aF, qF[kk], s1, 0, 0, 0);
        }
        __builtin_amdgcn_s_setprio(0);
        f32x4 sv = s0 + s1;                   // lane: e = 16et+4gi+r, t = 16tl+li
        float pml = fmaxf(fmaxf(sv[0], sv[1]), fmaxf(sv[2], sv[3]));
        pml = fmaxf(pml, __shfl_xor(pml, 16));
        pml = fmaxf(pml, __shfl_xor(pml, 32)); // max over this wave's 16 e, per t
        if (lane < 16) *(float*)(sm + OMX + wv * 64 + 4 * li) = pml;
        __syncthreads();                                   // B1

        // ---- phase B: softmax(ch) ∥ PV(ch-1) ∥ cvt/Khi/loads (R9 order) ----
        float pmO = *(const float*)(sm + OMX + (wv ^ 1) * 64 + 4 * li);
        bool doR = false;
        f16x8 bP[4];
        if (doPV) {
            const uint4* fp = (const uint4*)(sm + OFLG + 32 * qb);
            uint4 f0 = fp[0], f1 = fp[1];
            doR = (f0.x | f0.y | f0.z | f0.w | f1.x | f1.y | f1.z | f1.w) != 0;
            #pragma unroll
            for (int tt = 0; tt < 4; ++tt)
                bP[tt] = *(const f16x8*)(sm + OP + OPSZ * qb + (16 * tt + li) * 80 + 16 * gi);
        }
        // softmax: pm is already the FULL 32-e max for t (no slow-path shfl)
        {
            float pm = fmaxf(pml, pmO);
            bool trip = pm > mrun + 8.0f;                  // T13 defer-max
            unsigned long long bal = __ballot(trip);
            float alpha = 1.0f;
            if (bal != 0ULL) {                             // wave-uniform slow path
                float mnew = fmaxf(mrun, pm);
                alpha = exp2f((mrun - mnew) * L2E);
                lpart *= alpha;
                mrun = mnew;
            }
            f32x4 p4;
            #pragma unroll
            for (int j = 0; j < 4; ++j) p4[j] = exp2f((sv[j] - mrun) * L2E);
            lpart += p4[0] + p4[1] + p4[2] + p4[3];
            f16x4 pw = {(f16)p4[0], (f16)p4[1], (f16)p4[2], (f16)p4[3]};
            *(f16x4*)(sm + OP + OPSZ * pb + (16 * tl + li) * 80 + 32 * et + 8 * gi) = pw;
            if (et == 0 && lane < 16) *(float*)(sm + OAL + 256 * pb + 4 * (16 * tl + li)) = alpha;
            if (lane == 0) *(unsigned*)(sm + OFLG + 32 * pb + 4 * wv) = (bal != 0ULL) ? 1u : 0u;
        }
        // PV(ch-1): KT holds chunk ch-1 (written in phase C of iter ch-1)
        if (doPV) {
            if (doR) {
                float av[4];
                #pragma unroll
                for (int tt = 0; tt < 4; ++tt)
                    av[tt] = *(const float*)(sm + OAL + 256 * qb + 4 * (16 * tt + li));
                #pragma unroll
                for (int md = 0; md < 4; ++md)
                    #pragma unroll
                    for (int tt = 0; tt < 4; ++tt)
                        #pragma unroll
                        for (int r = 0; r < 4; ++r) ctx[md][tt][r] *= av[tt];
            }
            __builtin_amdgcn_s_setprio(1);
            #pragma unroll
            for (int md = 0; md < 4; ++md) {
                int dv = 64 * wv + 16 * md + li;
                int sig = ((dv >> 3) & 3) << 4;
                f16x8 a = *(const f16x8*)(sm + OKT + dv * 80 + ((16 * gi) ^ sig));
                #pragma unroll
                for (int tt = 0; tt < 4; ++tt)
                    ctx[md][tt] = __builtin_amdgcn_mfma_f32_16x16x32_f16(a, bP[tt], ctx[md][tt], 0, 0, 0);
            }
            __builtin_amdgcn_s_setprio(0);
        }
        // cvt st(ch+1) -> hvA + Khi-write(ch+1); issue loads(ch+2)  [R9 order]
        f16x4 hvA[8];
        if (more) {
            #pragma unroll
            for (int i = 0; i < 8; ++i) {
                f16x4 h4 = {(f16)st[i][0], (f16)st[i][1], (f16)st[i][2], (f16)st[i][3]};
                hvA[i] = h4;
                *(f16x4*)(kWr + i * KROW) = h4;
            }
            if (ch + 2 < NCH) {
                const float* src = encB + (size_t)(ch + 2) * EBLK * DD;
                #pragma unroll
                for (int i = 0; i < 8; ++i)
                    st[i] = *(const f32x4*)(src + (size_t)(8 * rb + i) * DD + 4 * c4);
            }
        }
        __syncthreads();                                   // B2
        // ---- phase C: KT-write(ch) from hvB ----
        #pragma unroll
        for (int k = 0; k < 4; ++k) {
            int d = 4 * c4 + k;
            int sig = ((d >> 3) & 3) << 4;
            f16x8 q8 = {hvB[0][k], hvB[1][k], hvB[2][k], hvB[3][k],
                        hvB[4][k], hvB[5][k], hvB[6][k], hvB[7][k]};
            *(f16x8*)(sm + OKT + d * 80 + ((16 * rb) ^ sig)) = q8;
        }
        if (more) {
            #pragma unroll
            for (int i = 0; i < 8; ++i) hvB[i] = hvA[i];
        }
    }

    __syncthreads();   // KT(NCH-1) written in last phase C

    // ---- final PV(NCH-1) ----
    {
        const int qb2 = (NCH - 1) & 1;
        const uint4* fp = (const uint4*)(sm + OFLG + 32 * qb2);
        uint4 f0 = fp[0], f1 = fp[1];
        bool doR = (f0.x | f0.y | f0.z | f0.w | f1.x | f1.y | f1.z | f1.w) != 0;
        f16x8 bP[4];
        #pragma unroll
        for (int tt = 0; tt < 4; ++tt)
            bP[tt] = *(const f16x8*)(sm + OP + OPSZ * qb2 + (16 * tt + li) * 80 + 16 * gi);
        if (doR) {
            float av[4];
            #pragma unroll
            for (int tt = 0; tt < 4; ++tt)
                av[tt] = *(const float*)(sm + OAL + 256 * qb2 + 4 * (16 * tt + li));
            #pragma unroll
            for (int md = 0; md < 4; ++md)
                #pragma unroll
                for (int tt = 0; tt < 4; ++tt)
                    #pragma unroll
                    for (int r = 0; r < 4; ++r) ctx[md][tt][r] *= av[tt];
        }
        #pragma unroll
        for (int md = 0; md < 4; ++md) {
            int dv = 64 * wv + 16 * md + li;
            int sig = ((dv >> 3) & 3) << 4;
            f16x8 a = *(const f16x8*)(sm + OKT + dv * 80 + ((16 * gi) ^ sig));
            #pragma unroll
            for (int tt = 0; tt < 4; ++tt)
                ctx[md][tt] = __builtin_amdgcn_mfma_f32_16x16x32_f16(a, bP[tt], ctx[md][tt], 0, 0, 0);
        }
    }

    // ---- epilogue: l reduce (gi-shfl + cross-et via OLL), normalize, write ----
    {
        float ps = lpart;
        ps += __shfl_xor(ps, 16);
        ps += __shfl_xor(ps, 32);             // sum over gi: wave's 16-e half per t
        if (et == 0 && lane < 16) *(float*)(sm + OLL + 4 * (16 * tl + li)) = ps;
        __syncthreads();
        if (et == 1 && lane < 16) {
            float* p = (float*)(sm + OLL + 4 * (16 * tl + li));
            *p += ps;
        }
    }
    __syncthreads();
    float inv[4];
    #pragma unroll
    for (int tt = 0; tt < 4; ++tt)
        inv[tt] = 1.0f / *(const float*)(sm + OLL + 4 * (16 * tt + li));
    #pragma unroll
    for (int md = 0; md < 4; ++md)
        #pragma unroll
        for (int tt = 0; tt < 4; ++tt) {
            int t = t0 + 16 * tt + li;
            int d = 64 * wv + 16 * md + 4 * gi;
            float4 o;
            o.x = ctx[md][tt][0] * inv[tt];
            o.y = ctx[md][tt][1] * inv[tt];
            o.z = ctx[md][tt][2] * inv[tt];
            o.w = ctx[md][tt][3] * inv[tt];
            *(float4*)(outB + (size_t)t * (2 * DD) + DD + d) = o;
        }
    #pragma unroll
    for (int it = 0; it < TBLK * (DD / 4) / 512; ++it) {
        int i = tid + it * 512;
        int t = i >> 7, cc = i & 127;
        float4 q = ((const float4*)(decB + (size_t)(t0 + t) * DD))[cc];
        ((float4*)(outB + (size_t)(t0 + t) * (2 * DD)))[cc] = q;
    }
}

extern "C" void kernel_launch(void* const* d_in, const int* in_sizes, int n_in,
                              void* d_out, int out_size, void* d_ws, size_t ws_size,
                              hipStream_t stream) {
    const float* enc = (const float*)d_in[0];
    const float* dec = (const float*)d_in[1];
    float* out = (float*)d_out;
    dim3 grid(NB * (TD / TBLK));   // 256 blocks: b = bid&7 (XCD pin), ttile = bid>>3
    dim3 block(512);
    attn_fused<<<grid, block, 0, stream>>>(enc, dec, out);
}

// Round 12
// 142.935 us; speedup vs baseline: 1.0099x; 1.0036x over previous
//
#include <hip/hip_runtime.h>

// Fused cross-attention: out = concat(dec, softmax_e(enc·dec^T)^T-weighted enc)
// B=8, T_enc=T_dec=2048, D=512, fp32 in/out.
// R12: merged-MFMA schedule. Phase A = QK(ch) + PV(ch-1) back-to-back (32
//      MFMA/wave dense, 20 independent accumulators); phase S = softmax(ch) +
//      KT-write(ch) + Khi-write(ch+1) + loads(ch+2). 2 barriers/iter.
//      P/alpha/flags single-buffered (schedule-separated). R9 math/swizzles.

typedef _Float16 f16;
typedef f16 f16x8 __attribute__((ext_vector_type(8)));
typedef f16 f16x4 __attribute__((ext_vector_type(4)));
typedef float f32x4 __attribute__((ext_vector_type(4)));

#define NB 8
#define TE 2048
#define TD 2048
#define DD 512
#define TBLK 64
#define EBLK 32
#define NCH (TE / EBLK)

// LDS layout (bytes) — audited: end 116256 < 163840
#define OKHI 0          // [32 e][512 d] f16 = 32768B, 1024B swizzled rows (QK A)
#define OKT  32768      // [512 d][40 e] f16 = 40960B, 80B rows, sig-swizzled (PV A)
#define OS4  73728      // 4 kq x [64 t][36 e] f32 = 36864B (144B rows)
#define OP   110592     // [64 t][40 e] f16 = 5120B, 80B rows (single buffer)
#define OAL  115712     // 64 f32 alpha (single buffer)
#define OLL  115968     // 64 f32 l
#define OFLG 116224     // 8 u32 rescale flags (single buffer)
#define SMEM_BYTES 116256

__device__ __forceinline__ int swz1k(int row, int byteInRow) {
    return row * 1024 + (byteInRow ^ ((row & 7) << 4));
}

__global__ __launch_bounds__(512, 2)
void attn_fused(const float* __restrict__ enc, const float* __restrict__ dec,
                float* __restrict__ out) {
    __shared__ __align__(16) char sm[SMEM_BYTES];
    const int tid  = threadIdx.x;
    const int b    = blockIdx.x & 7;          // XCD-pinned batch
    const int t0   = (blockIdx.x >> 3) * TBLK;
    const int lane = tid & 63;
    const int wv   = tid >> 6;
    const int li   = lane & 15;
    const int gi   = lane >> 4;
    const int tq   = wv & 1;                  // t-half: rows 32tq..32tq+31
    const int kq   = wv >> 1;                 // k-slice: d in [128kq, 128kq+128)
    const float L2E = 1.44269504088896f;

    const float* encB = enc + (size_t)b * TE * DD;
    const float* decB = dec + (size_t)b * TD * DD;
    float*       outB = out + (size_t)b * TD * (2 * DD);

    // staging map: c4 = d-quad 0..127, rb = e-octet 0..3 (e rows 8rb..8rb+7)
    const int c4 = tid & 127;
    const int rb = tid >> 7;

    // ---- issue K0 loads ----
    f32x4 st[8];
    #pragma unroll
    for (int i = 0; i < 8; ++i)
        st[i] = *(const f32x4*)(encB + (size_t)(8 * rb + i) * DD + 4 * c4);

    // ---- Q fragments (f16) direct from global ----
    f16x8 qF[4][2];
    #pragma unroll
    for (int kk = 0; kk < 4; ++kk)
        #pragma unroll
        for (int tl = 0; tl < 2; ++tl) {
            const float* qp = decB + (size_t)(t0 + 32 * tq + 16 * tl + li) * DD
                            + 128 * kq + 32 * kk + 8 * gi;
            f32x4 q0 = *(const f32x4*)qp;
            f32x4 q1 = *(const f32x4*)(qp + 4);
            f16x8 h;
            #pragma unroll
            for (int j = 0; j < 4; ++j) { h[j] = (f16)q0[j]; h[4 + j] = (f16)q1[j]; }
            qF[kk][tl] = h;
        }

    // ---- cvt K0 -> hvB + Khi-write(0); KT(0) written in phase S of iter 0 ----
    f16x4 hvB[8];
    #pragma unroll
    for (int i = 0; i < 8; ++i) {
        f16x4 h4 = {(f16)st[i][0], (f16)st[i][1], (f16)st[i][2], (f16)st[i][3]};
        hvB[i] = h4;
        *(f16x4*)(sm + OKHI + swz1k(8 * rb + i, 8 * c4)) = h4;
    }
    // issue K1 loads
    #pragma unroll
    for (int i = 0; i < 8; ++i)
        st[i] = *(const f32x4*)(encB + (size_t)(EBLK + 8 * rb + i) * DD + 4 * c4);
    __syncthreads();

    // softmax ownership: wave owns t-cols [8wv, 8wv+8); 8 lanes/col, 4 e/lane
    const int cq   = lane & 7;
    const int erq  = lane >> 3;               // 0..7 -> e rows 4erq..4erq+3
    const int tcol = 8 * wv + cq;
    float mrun = -1.0e30f;
    float lpart = 0.0f;                       // per-lane partial of l (4 e-slots)

    f32x4 ctx[4][4];                          // d [64wv,64wv+64) x t [0,64)
    #pragma unroll
    for (int md = 0; md < 4; ++md)
        #pragma unroll
        for (int tt = 0; tt < 4; ++tt)
            ctx[md][tt] = (f32x4){0.f, 0.f, 0.f, 0.f};

    for (int ch = 0; ch < NCH; ++ch) {
        const bool doPV = (ch > 0);
        const bool more = (ch + 1 < NCH);

        // ---- phase A: PV-operand reads + ctx rescale, then QK(ch) + PV(ch-1)
        //      as one dense MFMA block; S4 partial writes; B1. ----
        f16x8 bP[4];
        if (doPV) {
            const uint4* fp = (const uint4*)(sm + OFLG);
            uint4 f0 = fp[0], f1 = fp[1];
            bool doR = (f0.x | f0.y | f0.z | f0.w | f1.x | f1.y | f1.z | f1.w) != 0;
            #pragma unroll
            for (int tt = 0; tt < 4; ++tt)
                bP[tt] = *(const f16x8*)(sm + OP + (16 * tt + li) * 80 + 16 * gi);
            if (doR) {
                float av[4];
                #pragma unroll
                for (int tt = 0; tt < 4; ++tt)
                    av[tt] = *(const float*)(sm + OAL + 4 * (16 * tt + li));
                #pragma unroll
                for (int md = 0; md < 4; ++md)
                    #pragma unroll
                    for (int tt = 0; tt < 4; ++tt)
                        #pragma unroll
                        for (int r = 0; r < 4; ++r) ctx[md][tt][r] *= av[tt];
            }
        }
        f32x4 sacc[2][2];
        #pragma unroll
        for (int et = 0; et < 2; ++et)
            #pragma unroll
            for (int tl = 0; tl < 2; ++tl)
                sacc[et][tl] = (f32x4){0.f, 0.f, 0.f, 0.f};
        __builtin_amdgcn_s_setprio(1);
        #pragma unroll
        for (int kk = 0; kk < 4; ++kk) {
            int cb = 256 * kq + 64 * kk + 16 * gi;
            f16x8 aF[2];
            #pragma unroll
            for (int et = 0; et < 2; ++et)
                aF[et] = *(const f16x8*)(sm + OKHI + swz1k(16 * et + li, cb));
            #pragma unroll
            for (int et = 0; et < 2; ++et)
                #pragma unroll
                for (int tl = 0; tl < 2; ++tl)
                    sacc[et][tl] = __builtin_amdgcn_mfma_f32_16x16x32_f16(aF[et], qF[kk][tl], sacc[et][tl], 0, 0, 0);
        }
        if (doPV) {
            #pragma unroll
            for (int md = 0; md < 4; ++md) {
                int dv = 64 * wv + 16 * md + li;
                int sig = ((dv >> 3) & 3) << 4;
                f16x8 a = *(const f16x8*)(sm + OKT + dv * 80 + ((16 * gi) ^ sig));
                #pragma unroll
                for (int tt = 0; tt < 4; ++tt)
                    ctx[md][tt] = __builtin_amdgcn_mfma_f32_16x16x32_f16(a, bP[tt], ctx[md][tt], 0, 0, 0);
            }
        }
        __builtin_amdgcn_s_setprio(0);
        #pragma unroll
        for (int et = 0; et < 2; ++et)
            #pragma unroll
            for (int tl = 0; tl < 2; ++tl)
                *(f32x4*)(sm + OS4 + kq * 9216 + (32 * tq + 16 * tl + li) * 144
                          + (16 * et + 4 * gi) * 4) = sacc[et][tl];
        __syncthreads();                                   // B1

        // ---- phase S: softmax(ch) + KT-write(ch) + Khi(ch+1) + loads(ch+2) ----
        f32x4 s4 = (f32x4){0.f, 0.f, 0.f, 0.f};
        #pragma unroll
        for (int bu = 0; bu < 4; ++bu)
            s4 += *(const f32x4*)(sm + OS4 + bu * 9216 + tcol * 144 + 16 * erq);
        {
            float pml = fmaxf(fmaxf(s4[0], s4[1]), fmaxf(s4[2], s4[3]));
            bool trip = pml > mrun + 8.0f;                 // T13 defer-max
            unsigned long long bal = __ballot(trip);
            float alpha = 1.0f;
            if (bal != 0ULL) {                             // wave-uniform slow path
                float pm = pml;
                pm = fmaxf(pm, __shfl_xor(pm, 8));
                pm = fmaxf(pm, __shfl_xor(pm, 16));
                pm = fmaxf(pm, __shfl_xor(pm, 32));
                float mnew = fmaxf(mrun, pm);
                alpha = exp2f((mrun - mnew) * L2E);
                lpart *= alpha;
                mrun = mnew;
            }
            f32x4 p4;
            #pragma unroll
            for (int j = 0; j < 4; ++j) p4[j] = exp2f((s4[j] - mrun) * L2E);
            lpart += p4[0] + p4[1] + p4[2] + p4[3];
            f16x4 pw = {(f16)p4[0], (f16)p4[1], (f16)p4[2], (f16)p4[3]};
            *(f16x4*)(sm + OP + tcol * 80 + 8 * erq) = pw;
            if (erq == 0) *(float*)(sm + OAL + 4 * tcol) = alpha;
            if (lane == 0) *(unsigned*)(sm + OFLG + 4 * wv) = (bal != 0ULL) ? 1u : 0u;
        }
        // KT-write(ch) from hvB (PV(ch-1) reads ended at B1; PV(ch) reads after B2)
        #pragma unroll
        for (int k = 0; k < 4; ++k) {
            int d = 4 * c4 + k;
            int sig = ((d >> 3) & 3) << 4;
            f16x8 q8 = {hvB[0][k], hvB[1][k], hvB[2][k], hvB[3][k],
                        hvB[4][k], hvB[5][k], hvB[6][k], hvB[7][k]};
            *(f16x8*)(sm + OKT + d * 80 + ((16 * rb) ^ sig)) = q8;
        }
        // cvt st(ch+1) -> hvA + Khi-write(ch+1); issue loads(ch+2)
        if (more) {
            f16x4 hvA[8];
            #pragma unroll
            for (int i = 0; i < 8; ++i) {
                f16x4 h4 = {(f16)st[i][0], (f16)st[i][1], (f16)st[i][2], (f16)st[i][3]};
                hvA[i] = h4;
                *(f16x4*)(sm + OKHI + swz1k(8 * rb + i, 8 * c4)) = h4;
            }
            if (ch + 2 < NCH) {
                const float* src = encB + (size_t)(ch + 2) * EBLK * DD;
                #pragma unroll
                for (int i = 0; i < 8; ++i)
                    st[i] = *(const f32x4*)(src + (size_t)(8 * rb + i) * DD + 4 * c4);
            }
            #pragma unroll
            for (int i = 0; i < 8; ++i) hvB[i] = hvA[i];
        }
        __syncthreads();                                   // B2
    }

    // ---- final PV(NCH-1): KT/P/alpha/flags from iter NCH-1's phase S ----
    {
        const uint4* fp = (const uint4*)(sm + OFLG);
        uint4 f0 = fp[0], f1 = fp[1];
        bool doR = (f0.x | f0.y | f0.z | f0.w | f1.x | f1.y | f1.z | f1.w) != 0;
        f16x8 bP[4];
        #pragma unroll
        for (int tt = 0; tt < 4; ++tt)
            bP[tt] = *(const f16x8*)(sm + OP + (16 * tt + li) * 80 + 16 * gi);
        if (doR) {
            float av[4];
            #pragma unroll
            for (int tt = 0; tt < 4; ++tt)
                av[tt] = *(const float*)(sm + OAL + 4 * (16 * tt + li));
            #pragma unroll
            for (int md = 0; md < 4; ++md)
                #pragma unroll
                for (int tt = 0; tt < 4; ++tt)
                    #pragma unroll
                    for (int r = 0; r < 4; ++r) ctx[md][tt][r] *= av[tt];
        }
        #pragma unroll
        for (int md = 0; md < 4; ++md) {
            int dv = 64 * wv + 16 * md + li;
            int sig = ((dv >> 3) & 3) << 4;
            f16x8 a = *(const f16x8*)(sm + OKT + dv * 80 + ((16 * gi) ^ sig));
            #pragma unroll
            for (int tt = 0; tt < 4; ++tt)
                ctx[md][tt] = __builtin_amdgcn_mfma_f32_16x16x32_f16(a, bP[tt], ctx[md][tt], 0, 0, 0);
        }
    }

    // ---- epilogue: reduce per-lane l partials once, normalize, write ----
    {
        float ps = lpart;
        ps += __shfl_xor(ps, 8);
        ps += __shfl_xor(ps, 16);
        ps += __shfl_xor(ps, 32);
        if (erq == 0) *(float*)(sm + OLL + 4 * tcol) = ps;
    }
    __syncthreads();
    float inv[4];
    #pragma unroll
    for (int tt = 0; tt < 4; ++tt)
        inv[tt] = 1.0f / *(const float*)(sm + OLL + 4 * (16 * tt + li));
    #pragma unroll
    for (int md = 0; md < 4; ++md)
        #pragma unroll
        for (int tt = 0; tt < 4; ++tt) {
            int t = t0 + 16 * tt + li;
            int d = 64 * wv + 16 * md + 4 * gi;
            float4 o;
            o.x = ctx[md][tt][0] * inv[tt];
            o.y = ctx[md][tt][1] * inv[tt];
            o.z = ctx[md][tt][2] * inv[tt];
            o.w = ctx[md][tt][3] * inv[tt];
            *(float4*)(outB + (size_t)t * (2 * DD) + DD + d) = o;
        }
    #pragma unroll
    for (int it = 0; it < TBLK * (DD / 4) / 512; ++it) {
        int i = tid + it * 512;
        int t = i >> 7, cc = i & 127;
        float4 q = ((const float4*)(decB + (size_t)(t0 + t) * DD))[cc];
        ((float4*)(outB + (size_t)(t0 + t) * (2 * DD)))[cc] = q;
    }
}

extern "C" void kernel_launch(void* const* d_in, const int* in_sizes, int n_in,
                              void* d_out, int out_size, void* d_ws, size_t ws_size,
                              hipStream_t stream) {
    const float* enc = (const float*)d_in[0];
    const float* dec = (const float*)d_in[1];
    float* out = (float*)d_out;
    dim3 grid(NB * (TD / TBLK));   // 256 blocks: b = bid&7 (XCD pin), ttile = bid>>3
    dim3 block(512);
    attn_fused<<<grid, block, 0, stream>>>(enc, dec, out);
}

// Round 13
// 134.613 us; speedup vs baseline: 1.0723x; 1.0618x over previous
//
#include <hip/hip_runtime.h>

// Fused cross-attention: out = concat(dec, softmax_e(enc·dec^T)^T-weighted enc)
// B=8, T_enc=T_dec=2048, D=512, fp32 in/out.
// R13: R9 with QK wave mapping (et,kq) instead of (tq,kq): each wave computes
//      S[16e x 64t] for its 128-d k-slice -> aF LDS reads halve (no pair-wise
//      duplication; 32KB/chunk/CU for the 32KB K chunk). qF doubles to 64 regs.
//      Everything else (S4 merge, softmax fast path, PV, staging, defer-max,
//      2-barrier pipeline, deferred KT-write) byte-identical to R9.

typedef _Float16 f16;
typedef f16 f16x8 __attribute__((ext_vector_type(8)));
typedef f16 f16x4 __attribute__((ext_vector_type(4)));
typedef float f32x4 __attribute__((ext_vector_type(4)));

#define NB 8
#define TE 2048
#define TD 2048
#define DD 512
#define TBLK 64
#define EBLK 32
#define NCH (TE / EBLK)

// LDS layout (bytes) — audited: end 121664 < 163840
#define OKHI 0          // [32 e][512 d] f16 = 32768B, 1024B swizzled rows (QK A)
#define OKT  32768      // [512 d][40 e] f16 = 40960B, 80B rows, sig-swizzled (PV A)
#define OS4  73728      // 4 kq x [64 t][36 e] f32 = 36864B (144B rows)
#define OP   110592     // 2 x [64 t][40 e] f16 = 10240B, 80B rows
#define OPSZ 5120
#define OAL  120832     // 2 x 64 f32 alpha
#define OLL  121344     // 64 f32 l
#define OFLG 121600     // 2 x 8 u32 rescale flags
#define SMEM_BYTES 121664

__device__ __forceinline__ int swz1k(int row, int byteInRow) {
    return row * 1024 + (byteInRow ^ ((row & 7) << 4));
}

__global__ __launch_bounds__(512, 2)
void attn_fused(const float* __restrict__ enc, const float* __restrict__ dec,
                float* __restrict__ out) {
    __shared__ __align__(16) char sm[SMEM_BYTES];
    const int tid  = threadIdx.x;
    const int b    = blockIdx.x & 7;          // XCD-pinned batch
    const int t0   = (blockIdx.x >> 3) * TBLK;
    const int lane = tid & 63;
    const int wv   = tid >> 6;
    const int li   = lane & 15;
    const int gi   = lane >> 4;
    const int et   = wv & 1;                  // e-tile: e in [16et, 16et+16)
    const int kq   = wv >> 1;                 // k-slice: d in [128kq, 128kq+128)
    const float L2E = 1.44269504088896f;

    const float* encB = enc + (size_t)b * TE * DD;
    const float* decB = dec + (size_t)b * TD * DD;
    float*       outB = out + (size_t)b * TD * (2 * DD);

    // staging map: c4 = d-quad 0..127, rb = e-octet 0..3 (e rows 8rb..8rb+7)
    const int c4 = tid & 127;
    const int rb = tid >> 7;

    // ---- issue K0 loads ----
    f32x4 st[8];
    #pragma unroll
    for (int i = 0; i < 8; ++i)
        st[i] = *(const f32x4*)(encB + (size_t)(8 * rb + i) * DD + 4 * c4);

    // ---- Q fragments (f16) direct from global: all 64 t, k-slice kq ----
    f16x8 qF[4][4];
    #pragma unroll
    for (int kk = 0; kk < 4; ++kk)
        #pragma unroll
        for (int tl = 0; tl < 4; ++tl) {
            const float* qp = decB + (size_t)(t0 + 16 * tl + li) * DD
                            + 128 * kq + 32 * kk + 8 * gi;
            f32x4 q0 = *(const f32x4*)qp;
            f32x4 q1 = *(const f32x4*)(qp + 4);
            f16x8 h;
            #pragma unroll
            for (int j = 0; j < 4; ++j) { h[j] = (f16)q0[j]; h[4 + j] = (f16)q1[j]; }
            qF[kk][tl] = h;
        }

    // ---- cvt K0 -> hvB + Khi-write(0); KT(0) written in iter 0 phase C ----
    f16x4 hvB[8];
    #pragma unroll
    for (int i = 0; i < 8; ++i) {
        f16x4 h4 = {(f16)st[i][0], (f16)st[i][1], (f16)st[i][2], (f16)st[i][3]};
        hvB[i] = h4;
        *(f16x4*)(sm + OKHI + swz1k(8 * rb + i, 8 * c4)) = h4;
    }
    // issue K1 loads
    #pragma unroll
    for (int i = 0; i < 8; ++i)
        st[i] = *(const f32x4*)(encB + (size_t)(EBLK + 8 * rb + i) * DD + 4 * c4);
    __syncthreads();

    // softmax ownership: wave owns t-cols [8wv, 8wv+8); 8 lanes/col, 4 e/lane
    const int cq   = lane & 7;
    const int erq  = lane >> 3;               // 0..7 -> e rows 4erq..4erq+3
    const int tcol = 8 * wv + cq;
    float mrun = -1.0e30f;
    float lpart = 0.0f;                       // per-lane partial of l (4 e-slots)

    f32x4 ctx[4][4];                          // d [64wv,64wv+64) x t [0,64)
    #pragma unroll
    for (int md = 0; md < 4; ++md)
        #pragma unroll
        for (int tt = 0; tt < 4; ++tt)
            ctx[md][tt] = (f32x4){0.f, 0.f, 0.f, 0.f};

    for (int ch = 0; ch < NCH; ++ch) {
        const int pb = ch & 1;
        const int qb = pb ^ 1;
        const bool doPV = (ch > 0);
        const bool more = (ch + 1 < NCH);

        // ---- phase A: QK(ch), S4 partial writes ----
        // wave (et,kq): S[16et..16et+16) x [0,64) for d in [128kq,128kq+128)
        f32x4 sacc[4];
        #pragma unroll
        for (int tl = 0; tl < 4; ++tl)
            sacc[tl] = (f32x4){0.f, 0.f, 0.f, 0.f};
        __builtin_amdgcn_s_setprio(1);
        #pragma unroll
        for (int kk = 0; kk < 4; ++kk) {
            int cb = 256 * kq + 64 * kk + 16 * gi;
            f16x8 aF = *(const f16x8*)(sm + OKHI + swz1k(16 * et + li, cb));
            #pragma unroll
            for (int tl = 0; tl < 4; ++tl)
                sacc[tl] = __builtin_amdgcn_mfma_f32_16x16x32_f16(aF, qF[kk][tl], sacc[tl], 0, 0, 0);
        }
        __builtin_amdgcn_s_setprio(0);
        #pragma unroll
        for (int tl = 0; tl < 4; ++tl)
            *(f32x4*)(sm + OS4 + kq * 9216 + (16 * tl + li) * 144
                      + (16 * et + 4 * gi) * 4) = sacc[tl];
        __syncthreads();                                   // B1

        // ---- phase B: softmax(ch) ∥ PV(ch-1) ∥ Khi(ch+1) ∥ loads(ch+2) ----
        f32x4 s4 = (f32x4){0.f, 0.f, 0.f, 0.f};
        #pragma unroll
        for (int bu = 0; bu < 4; ++bu)
            s4 += *(const f32x4*)(sm + OS4 + bu * 9216 + tcol * 144 + 16 * erq);

        bool doR = false;
        f16x8 bP[4];
        if (doPV) {
            const uint4* fp = (const uint4*)(sm + OFLG + 32 * qb);
            uint4 f0 = fp[0], f1 = fp[1];
            doR = (f0.x | f0.y | f0.z | f0.w | f1.x | f1.y | f1.z | f1.w) != 0;
            #pragma unroll
            for (int tt = 0; tt < 4; ++tt)
                bP[tt] = *(const f16x8*)(sm + OP + OPSZ * qb + (16 * tt + li) * 80 + 16 * gi);
        }
        // softmax(ch): fast path has zero cross-lane ops
        {
            float pml = fmaxf(fmaxf(s4[0], s4[1]), fmaxf(s4[2], s4[3]));
            bool trip = pml > mrun + 8.0f;                 // T13 defer-max
            unsigned long long bal = __ballot(trip);
            float alpha = 1.0f;
            if (bal != 0ULL) {                             // wave-uniform slow path
                float pm = pml;
                pm = fmaxf(pm, __shfl_xor(pm, 8));
                pm = fmaxf(pm, __shfl_xor(pm, 16));
                pm = fmaxf(pm, __shfl_xor(pm, 32));
                float mnew = fmaxf(mrun, pm);
                alpha = exp2f((mrun - mnew) * L2E);
                lpart *= alpha;
                mrun = mnew;
            }
            f32x4 p4;
            #pragma unroll
            for (int j = 0; j < 4; ++j) p4[j] = exp2f((s4[j] - mrun) * L2E);
            lpart += p4[0] + p4[1] + p4[2] + p4[3];
            f16x4 pw = {(f16)p4[0], (f16)p4[1], (f16)p4[2], (f16)p4[3]};
            *(f16x4*)(sm + OP + OPSZ * pb + tcol * 80 + 8 * erq) = pw;
            if (erq == 0) *(float*)(sm + OAL + 256 * pb + 4 * tcol) = alpha;
            if (lane == 0) *(unsigned*)(sm + OFLG + 32 * pb + 4 * wv) = (bal != 0ULL) ? 1u : 0u;
        }
        // PV(ch-1): KT holds chunk ch-1 (written in phase C of iter ch-1)
        if (doPV) {
            if (doR) {
                float av[4];
                #pragma unroll
                for (int tt = 0; tt < 4; ++tt)
                    av[tt] = *(const float*)(sm + OAL + 256 * qb + 4 * (16 * tt + li));
                #pragma unroll
                for (int md = 0; md < 4; ++md)
                    #pragma unroll
                    for (int tt = 0; tt < 4; ++tt)
                        #pragma unroll
                        for (int r = 0; r < 4; ++r) ctx[md][tt][r] *= av[tt];
            }
            __builtin_amdgcn_s_setprio(1);
            #pragma unroll
            for (int md = 0; md < 4; ++md) {
                int dv = 64 * wv + 16 * md + li;
                int sig = ((dv >> 3) & 3) << 4;
                f16x8 a = *(const f16x8*)(sm + OKT + dv * 80 + ((16 * gi) ^ sig));
                #pragma unroll
                for (int tt = 0; tt < 4; ++tt)
                    ctx[md][tt] = __builtin_amdgcn_mfma_f32_16x16x32_f16(a, bP[tt], ctx[md][tt], 0, 0, 0);
            }
            __builtin_amdgcn_s_setprio(0);
        }
        // cvt st(ch+1) -> hvA + Khi-write(ch+1); issue loads(ch+2)
        f16x4 hvA[8];
        if (more) {
            #pragma unroll
            for (int i = 0; i < 8; ++i) {
                f16x4 h4 = {(f16)st[i][0], (f16)st[i][1], (f16)st[i][2], (f16)st[i][3]};
                hvA[i] = h4;
                *(f16x4*)(sm + OKHI + swz1k(8 * rb + i, 8 * c4)) = h4;
            }
            if (ch + 2 < NCH) {
                const float* src = encB + (size_t)(ch + 2) * EBLK * DD;
                #pragma unroll
                for (int i = 0; i < 8; ++i)
                    st[i] = *(const f32x4*)(src + (size_t)(8 * rb + i) * DD + 4 * c4);
            }
        }
        __syncthreads();                                   // B2
        // ---- phase C: KT-write(ch) from hvB ----
        #pragma unroll
        for (int k = 0; k < 4; ++k) {
            int d = 4 * c4 + k;
            int sig = ((d >> 3) & 3) << 4;
            f16x8 q8 = {hvB[0][k], hvB[1][k], hvB[2][k], hvB[3][k],
                        hvB[4][k], hvB[5][k], hvB[6][k], hvB[7][k]};
            *(f16x8*)(sm + OKT + d * 80 + ((16 * rb) ^ sig)) = q8;
        }
        if (more) {
            #pragma unroll
            for (int i = 0; i < 8; ++i) hvB[i] = hvA[i];
        }
    }

    __syncthreads();   // KT(NCH-1) written in last phase C

    // ---- final PV(NCH-1) ----
    {
        const int qb2 = (NCH - 1) & 1;
        const uint4* fp = (const uint4*)(sm + OFLG + 32 * qb2);
        uint4 f0 = fp[0], f1 = fp[1];
        bool doR = (f0.x | f0.y | f0.z | f0.w | f1.x | f1.y | f1.z | f1.w) != 0;
        f16x8 bP[4];
        #pragma unroll
        for (int tt = 0; tt < 4; ++tt)
            bP[tt] = *(const f16x8*)(sm + OP + OPSZ * qb2 + (16 * tt + li) * 80 + 16 * gi);
        if (doR) {
            float av[4];
            #pragma unroll
            for (int tt = 0; tt < 4; ++tt)
                av[tt] = *(const float*)(sm + OAL + 256 * qb2 + 4 * (16 * tt + li));
            #pragma unroll
            for (int md = 0; md < 4; ++md)
                #pragma unroll
                for (int tt = 0; tt < 4; ++tt)
                    #pragma unroll
                    for (int r = 0; r < 4; ++r) ctx[md][tt][r] *= av[tt];
        }
        #pragma unroll
        for (int md = 0; md < 4; ++md) {
            int dv = 64 * wv + 16 * md + li;
            int sig = ((dv >> 3) & 3) << 4;
            f16x8 a = *(const f16x8*)(sm + OKT + dv * 80 + ((16 * gi) ^ sig));
            #pragma unroll
            for (int tt = 0; tt < 4; ++tt)
                ctx[md][tt] = __builtin_amdgcn_mfma_f32_16x16x32_f16(a, bP[tt], ctx[md][tt], 0, 0, 0);
        }
    }

    // ---- epilogue: reduce per-lane l partials once, normalize, write ----
    {
        float ps = lpart;
        ps += __shfl_xor(ps, 8);
        ps += __shfl_xor(ps, 16);
        ps += __shfl_xor(ps, 32);
        if (erq == 0) *(float*)(sm + OLL + 4 * tcol) = ps;
    }
    __syncthreads();
    float inv[4];
    #pragma unroll
    for (int tt = 0; tt < 4; ++tt)
        inv[tt] = 1.0f / *(const float*)(sm + OLL + 4 * (16 * tt + li));
    #pragma unroll
    for (int md = 0; md < 4; ++md)
        #pragma unroll
        for (int tt = 0; tt < 4; ++tt) {
            int t = t0 + 16 * tt + li;
            int d = 64 * wv + 16 * md + 4 * gi;
            float4 o;
            o.x = ctx[md][tt][0] * inv[tt];
            o.y = ctx[md][tt][1] * inv[tt];
            o.z = ctx[md][tt][2] * inv[tt];
            o.w = ctx[md][tt][3] * inv[tt];
            *(float4*)(outB + (size_t)t * (2 * DD) + DD + d) = o;
        }
    #pragma unroll
    for (int it = 0; it < TBLK * (DD / 4) / 512; ++it) {
        int i = tid + it * 512;
        int t = i >> 7, cc = i & 127;
        float4 q = ((const float4*)(decB + (size_t)(t0 + t) * DD))[cc];
        ((float4*)(outB + (size_t)(t0 + t) * (2 * DD)))[cc] = q;
    }
}

extern "C" void kernel_launch(void* const* d_in, const int* in_sizes, int n_in,
                              void* d_out, int out_size, void* d_ws, size_t ws_size,
                              hipStream_t stream) {
    const float* enc = (const float*)d_in[0];
    const float* dec = (const float*)d_in[1];
    float* out = (float*)d_out;
    dim3 grid(NB * (TD / TBLK));   // 256 blocks: b = bid&7 (XCD pin), ttile = bid>>3
    dim3 block(512);
    attn_fused<<<grid, block, 0, stream>>>(enc, dec, out);
}